// Round 1
// 741.579 us; speedup vs baseline: 1.0231x; 1.0231x over previous
//
#include <hip/hip_runtime.h>

#define KCOLS 7
#define MCOLS 8
#define LDSCH 768     // 4-row chunks cached in LDS  (3072 rows, 48 KB)
#define CACHECH 1024  // total cached chunks incl. 256 register chunks (4096 rows)
#define NB_PREF 512
#define TAGM 0x7fffffffu

typedef unsigned long long u64;

// self-validating word: high32 = tag (| stop bit31 for broadcast), low32 = f32 bits
__device__ __forceinline__ u64 mkword(unsigned tag, float v) {
    return ((u64)tag << 32) | (u64)__float_as_uint(v);
}
__device__ __forceinline__ void st_rel(u64* p, u64 w) {
    __hip_atomic_store(p, w, __ATOMIC_RELAXED, __HIP_MEMORY_SCOPE_AGENT);
}
__device__ __forceinline__ u64 ld_rel(const u64* p) {
    return __hip_atomic_load(p, __ATOMIC_RELAXED, __HIP_MEMORY_SCOPE_AGENT);
}

// round-to-nearest-even pack of two f32 into bf16x2 (lo=a, hi=b)
__device__ __forceinline__ uint32_t pk_bf16(float a, float b) {
    uint32_t ua = __float_as_uint(a), ub = __float_as_uint(b);
    ua += 0x7FFFu + ((ua >> 16) & 1u);
    ub += 0x7FFFu + ((ub >> 16) & 1u);
    return (ua >> 16) | (ub & 0xFFFF0000u);
}
__device__ __forceinline__ void unp(uint32_t u, float& lo, float& hi) {
    lo = __uint_as_float(u << 16);
    hi = __uint_as_float(u & 0xFFFF0000u);
}
__device__ __forceinline__ float rcp_nr(float d) {
    float r = __builtin_amdgcn_rcpf(d);
    return fmaf(fmaf(-d, r, 1.0f), r, r);  // one Newton step -> ~1e-7 rel
}
// q = softmax(p)^10 (f32), sq = sum q
__device__ __forceinline__ void softmax10(const float* p, float* q, float& sq) {
    float mx = p[0];
#pragma unroll
    for (int j = 1; j < KCOLS; ++j) mx = fmaxf(mx, p[j]);
    float s = 0.0f;
#pragma unroll
    for (int j = 0; j < KCOLS; ++j) s += __expf(p[j] - mx);
    const float ls10 = 10.0f * __logf(s);
    sq = 0.0f;
#pragma unroll
    for (int j = 0; j < KCOLS; ++j) {
        q[j] = __expf(fmaf(10.0f, p[j] - mx, -ls10));
        sq += q[j];
    }
}

__device__ __forceinline__ void setup_chunk(const float4* Pv, size_t f4base,
                                            float* acc, uint4* qq) {
    union { float4 v4[7]; float f[28]; } u;
#pragma unroll
    for (int i = 0; i < 7; ++i) u.v4[i] = Pv[f4base + i];
#pragma unroll
    for (int k = 0; k < 4; ++k) {
        float q[KCOLS], sq;
        softmax10(u.f + k * 7, q, sq);
        qq[k] = make_uint4(pk_bf16(q[0], q[1]), pk_bf16(q[2], q[3]),
                           pk_bf16(q[4], q[5]), pk_bf16(q[6], 1.0f));
        const float rr = rcp_nr(0.125f * (sq + 1.0f));   // fold iter 1, b0=1/8
#pragma unroll
        for (int j = 0; j < KCOLS; ++j) acc[j] = fmaf(q[j], rr, acc[j]);
        acc[KCOLS] += rr;
    }
}

__device__ __forceinline__ void cached_row(uint4 u, const float* bf, float* acc) {
    float f0, f1, f2, f3, f4, f5, f6, f7;
    unp(u.x, f0, f1); unp(u.y, f2, f3); unp(u.z, f4, f5); unp(u.w, f6, f7);
    float dot = f0 * bf[0];
    dot = fmaf(f1, bf[1], dot); dot = fmaf(f2, bf[2], dot);
    dot = fmaf(f3, bf[3], dot); dot = fmaf(f4, bf[4], dot);
    dot = fmaf(f5, bf[5], dot); dot = fmaf(f6, bf[6], dot);
    dot = fmaf(f7, bf[7], dot);
    const float rr = rcp_nr(dot);
    acc[0] = fmaf(f0, rr, acc[0]); acc[1] = fmaf(f1, rr, acc[1]);
    acc[2] = fmaf(f2, rr, acc[2]); acc[3] = fmaf(f3, rr, acc[3]);
    acc[4] = fmaf(f4, rr, acc[4]); acc[5] = fmaf(f5, rr, acc[5]);
    acc[6] = fmaf(f6, rr, acc[6]); acc[7] = fmaf(f7, rr, acc[7]);
}

__device__ __forceinline__ void stream_chunk(const float4* Pv, size_t f4base,
                                             const float* bf, float* acc) {
    union { float4 v4[7]; float f[28]; } u;
#pragma unroll
    for (int i = 0; i < 7; ++i) u.v4[i] = Pv[f4base + i];
#pragma unroll
    for (int k = 0; k < 4; ++k) {
        float q[KCOLS], sq;
        softmax10(u.f + k * 7, q, sq);
        float dot = bf[KCOLS];
#pragma unroll
        for (int j = 0; j < KCOLS; ++j) dot = fmaf(q[j], bf[j], dot);
        const float rr = rcp_nr(dot);
#pragma unroll
        for (int j = 0; j < KCOLS; ++j) acc[j] = fmaf(q[j], rr, acc[j]);
        acc[KCOLS] += rr;
    }
}

__device__ __forceinline__ void final_chunk(const float4* Pv, float4* Ov, size_t f4base,
                                            const float* bpf, const float* bfin) {
    union { float4 v4[7]; float f[28]; } u;
    union { float4 v4[7]; float f[28]; } o;
#pragma unroll
    for (int i = 0; i < 7; ++i) u.v4[i] = Pv[f4base + i];
#pragma unroll
    for (int k = 0; k < 4; ++k) {
        float q[KCOLS], sq;
        softmax10(u.f + k * 7, q, sq);
        float dot = bpf[KCOLS];
#pragma unroll
        for (int j = 0; j < KCOLS; ++j) dot = fmaf(q[j], bpf[j], dot);
        const float rr = rcp_nr(dot);
#pragma unroll
        for (int j = 0; j < KCOLS; ++j) o.f[k * 7 + j] = q[j] * bfin[j] * rr;
    }
#pragma unroll
    for (int i = 0; i < 7; ++i) Ov[f4base + i] = o.v4[i];
}

// Persistent cooperative Sinkhorn, FENCE-FREE leader-broadcast sync:
// all cross-block words are (tag<<32 | f32) relaxed agent atomics -> no
// buffer_inv / wbl2 storms. Single buffer (no parity): the dependency chain
// leader-consumes(it) -> broadcast(it) -> workers-publish(it+1) makes
// overwrite-before-read impossible; tags are strictly monotone.
// v7: BATCHED leader gather -- all 16 partial words are loaded as
// independent in-flight loads per retry round (1-2 memory round trips)
// instead of 16 serial dependent poll loops (~16 RTs on the critical path).
// pw[bx*8+j]: block partials.  bw[j]: leader's b broadcast (stop in bit63).
__global__ __launch_bounds__(256, 2)
void sinkhorn_v7(const float* __restrict__ P, float* __restrict__ out,
                 u64* __restrict__ pw, u64* __restrict__ bw,
                 int n, int nb, int rpb) {
    const int tid = threadIdx.x, bx = blockIdx.x;
    const int lane = tid & 63, wv = tid >> 6;
    const double inv_n = 1.0 / (double)n;
    const double fi = 1.0 / 1.1;  // GAMMA/(GAMMA+EPSILON)
    const double Pb[MCOLS] = {0.17, 0.14, 0.15, 0.12, 0.05, 0.13, 0.24, 0.0};

    __shared__ uint4 qsh[LDSCH * 4];     // 48 KB
    __shared__ double wred[4][MCOLS];
    __shared__ double bn_sh[MCOLS];
    __shared__ float bf_sh[MCOLS];
    __shared__ int stop_sh;

    const int row0 = bx * rpb;           // rpb multiple of 4
    int rows_here = n - row0;
    if (rows_here > rpb) rows_here = rpb;
    if (rows_here < 0) rows_here = 0;
    const int nch = rows_here >> 2;
    const int nlds = (nch < LDSCH) ? nch : LDSCH;
    const int ncached = (nch < CACHECH) ? nch : CACHECH;
    const size_t base4 = (size_t)(row0 >> 2) * 7;
    const float4* Pv = (const float4*)P;

    uint4 rq[4];
    const int crg = LDSCH + tid;
    const bool have_reg = (crg < ncached);

    // ---------------- setup pass: read P, cache q, fold iteration 1 --------
    float acc[MCOLS];
#pragma unroll
    for (int j = 0; j < MCOLS; ++j) acc[j] = 0.0f;

#pragma unroll
    for (int jj = 0; jj < 3; ++jj) {
        const int c = tid + 256 * jj;
        if (c < nlds) {
            uint4 qq[4];
            setup_chunk(Pv, base4 + (size_t)c * 7, acc, qq);
#pragma unroll
            for (int k = 0; k < 4; ++k) qsh[c * 4 + k] = qq[k];
        }
    }
    if (have_reg) setup_chunk(Pv, base4 + (size_t)crg * 7, acc, rq);
    for (int c = CACHECH + tid; c < nch; c += 256) {
        uint4 qq[4];
        setup_chunk(Pv, base4 + (size_t)c * 7, acc, qq);
    }
    for (int r = (nch << 2) + tid; r < rows_here; r += 256) {
        float p[KCOLS];
        const float* row = P + (size_t)(row0 + r) * KCOLS;
        for (int j = 0; j < KCOLS; ++j) p[j] = row[j];
        float q[KCOLS], sq;
        softmax10(p, q, sq);
        const float rr = rcp_nr(0.125f * (sq + 1.0f));
        for (int j = 0; j < KCOLS; ++j) acc[j] = fmaf(q[j], rr, acc[j]);
        acc[KCOLS] += rr;
    }

    // block reduce -> publish tagged partial words (tag 1)
#pragma unroll
    for (int j = 0; j < MCOLS; ++j) {
        float v = acc[j];
#pragma unroll
        for (int off = 32; off > 0; off >>= 1) v += __shfl_down(v, off, 64);
        if (lane == 0) wred[wv][j] = (double)v;
    }
    __syncthreads();
    if (tid < MCOLS)
        st_rel(pw + bx * MCOLS + tid,
               mkword(1u, (float)(wred[0][tid] + wred[1][tid] +
                                  wred[2][tid] + wred[3][tid])));

    // ---------------- Sinkhorn loop ---------------------------------------
    double b64[MCOLS];
#pragma unroll
    for (int j = 0; j < MCOLS; ++j) b64[j] = 0.125;
    float bff[MCOLS], bpf[MCOLS];
#pragma unroll
    for (int j = 0; j < MCOLS; ++j) { bff[j] = 0.125f; bpf[j] = 0.125f; }

    // leader gather stripes: nb <= 512 always (launch clamps), 256 threads
    const u64* wp0 = pw + (size_t)tid * MCOLS;
    const u64* wp1 = pw + (size_t)(tid + 256) * MCOLS;
    const bool h0 = (tid < nb);
    const bool h1 = (tid + 256 < nb);

    for (int it = 1; it <= 50; ++it) {
        const unsigned want = (unsigned)it;
        int stop;
        if (bx == 0) {
            // ---- leader: batched poll of all partials, reduce, broadcast --
            u64 w0[MCOLS], w1[MCOLS];
            for (;;) {
                unsigned bad = 0;
                if (h0) {
#pragma unroll
                    for (int j = 0; j < MCOLS; ++j) w0[j] = ld_rel(wp0 + j);
                }
                if (h1) {
#pragma unroll
                    for (int j = 0; j < MCOLS; ++j) w1[j] = ld_rel(wp1 + j);
                }
                if (h0) {
#pragma unroll
                    for (int j = 0; j < MCOLS; ++j)
                        bad |= ((unsigned)(w0[j] >> 32)) ^ want;
                }
                if (h1) {
#pragma unroll
                    for (int j = 0; j < MCOLS; ++j)
                        bad |= ((unsigned)(w1[j] >> 32)) ^ want;
                }
                if (!bad) break;
                __builtin_amdgcn_s_sleep(1);
            }
            double c8[MCOLS];
#pragma unroll
            for (int j = 0; j < MCOLS; ++j) {
                double v = 0.0;
                if (h0) v += (double)__uint_as_float((unsigned)w0[j]);
                if (h1) v += (double)__uint_as_float((unsigned)w1[j]);
                c8[j] = v;
            }
#pragma unroll
            for (int j = 0; j < MCOLS; ++j) {   // fixed f64 tree -> deterministic
                double v = c8[j];
#pragma unroll
                for (int off = 32; off > 0; off >>= 1) v += __shfl_down(v, off, 64);
                if (lane == 0) wred[wv][j] = v;
            }
            __syncthreads();
            if (tid < MCOLS) {
                double c = wred[0][tid] + wred[1][tid] + wred[2][tid] + wred[3][tid];
                c *= inv_n;
                bn_sh[tid] = (tid < KCOLS) ? pow(Pb[tid] / c, fi) : 0.0;
            }
            __syncthreads();
            double err2 = 0.0;
#pragma unroll
            for (int j = 0; j < MCOLS; ++j) {
                const double d = bn_sh[j] - b64[j];
                err2 += d * d;
            }
            stop = (err2 <= 1e-12 || it == 50) ? 1 : 0;
            if (tid < MCOLS)
                st_rel(bw + tid, mkword(want | (stop ? 0x80000000u : 0u),
                                        (float)bn_sh[tid]));
#pragma unroll
            for (int j = 0; j < MCOLS; ++j) {
                bpf[j] = (float)b64[j];
                b64[j] = bn_sh[j];
                bff[j] = (float)b64[j];
            }
        } else {
            // ---- follower: 8 threads poll the 8 broadcast words ----------
            if (tid < MCOLS) {
                u64 w;
                while ((unsigned)(((w = ld_rel(bw + tid)) >> 32) & TAGM) != want)
                    __builtin_amdgcn_s_sleep(1);
                bf_sh[tid] = __uint_as_float((unsigned)w);
                if (tid == 0) stop_sh = (int)(w >> 63);
            }
            __syncthreads();
            stop = stop_sh;
#pragma unroll
            for (int j = 0; j < MCOLS; ++j) {
                bpf[j] = bff[j];
                bff[j] = bf_sh[j];
            }
        }
        if (stop) break;

        // ---- compute pass with new b ----------------------------------
        float a2[MCOLS];
#pragma unroll
        for (int j = 0; j < MCOLS; ++j) a2[j] = 0.0f;
#pragma unroll
        for (int jj = 0; jj < 12; ++jj) {
            const int r = tid + 256 * jj;
            if (r < nlds * 4) cached_row(qsh[r], bff, a2);
        }
        if (have_reg) {
#pragma unroll
            for (int k = 0; k < 4; ++k) cached_row(rq[k], bff, a2);
        }
        for (int c = CACHECH + tid; c < nch; c += 256)
            stream_chunk(Pv, base4 + (size_t)c * 7, bff, a2);
        for (int r = (nch << 2) + tid; r < rows_here; r += 256) {
            float p2[KCOLS];
            const float* row = P + (size_t)(row0 + r) * KCOLS;
            for (int j = 0; j < KCOLS; ++j) p2[j] = row[j];
            float q[KCOLS], sq;
            softmax10(p2, q, sq);
            float dot = bff[KCOLS];
            for (int j = 0; j < KCOLS; ++j) dot = fmaf(q[j], bff[j], dot);
            const float rr = rcp_nr(dot);
            for (int j = 0; j < KCOLS; ++j) a2[j] = fmaf(q[j], rr, a2[j]);
            a2[KCOLS] += rr;
        }

#pragma unroll
        for (int j = 0; j < MCOLS; ++j) {
            float v = a2[j];
#pragma unroll
            for (int off = 32; off > 0; off >>= 1) v += __shfl_down(v, off, 64);
            if (lane == 0) wred[wv][j] = (double)v;
        }
        __syncthreads();
        if (tid < MCOLS)
            st_rel(pw + bx * MCOLS + tid,
                   mkword((unsigned)(it + 1),
                          (float)(wred[0][tid] + wred[1][tid] +
                                  wred[2][tid] + wred[3][tid])));
    }

    // ---------------- final pass: exact f32 q from P, write plan -----------
    float4* Ov = (float4*)out;
    for (int c = tid; c < nch; c += 256)
        final_chunk(Pv, Ov, base4 + (size_t)c * 7, bpf, bff);
    for (int r = (nch << 2) + tid; r < rows_here; r += 256) {
        float p[KCOLS];
        const float* row = P + (size_t)(row0 + r) * KCOLS;
        for (int j = 0; j < KCOLS; ++j) p[j] = row[j];
        float q[KCOLS], sq;
        softmax10(p, q, sq);
        float dot = bpf[KCOLS];
        for (int j = 0; j < KCOLS; ++j) dot = fmaf(q[j], bpf[j], dot);
        const float rr = rcp_nr(dot);
        float* orow = out + (size_t)(row0 + r) * KCOLS;
        for (int j = 0; j < KCOLS; ++j) orow[j] = q[j] * bff[j] * rr;
    }
}

extern "C" void kernel_launch(void* const* d_in, const int* in_sizes, int n_in,
                              void* d_out, int out_size, void* d_ws, size_t ws_size,
                              hipStream_t stream) {
    (void)n_in; (void)out_size;
    const float* P = (const float*)d_in[0];
    float* out = (float*)d_out;
    const int n = in_sizes[0] / KCOLS;

    int dev = 0;
    hipGetDevice(&dev);
    int cus = 0;
    hipDeviceGetAttribute(&cus, hipDeviceAttributeMultiprocessorCount, dev);
    if (cus <= 0) cus = 256;
    int maxb = 0;
    if (hipOccupancyMaxActiveBlocksPerMultiprocessor(&maxb, sinkhorn_v7, 256, 0) != hipSuccess || maxb < 1)
        maxb = 1;

    long long cap = (long long)maxb * cus;
    int nb = NB_PREF;
    if (nb > cap) nb = (int)cap;
    while (nb > 64 && (size_t)((nb * MCOLS + MCOLS) * sizeof(u64)) > ws_size) nb >>= 1;
    if (nb < 2) nb = 2;
    int rpb = (((n + nb - 1) / nb) + 3) & ~3;   // nb=512, n=2^21 -> 4096 exact

    u64* pw = (u64*)d_ws;
    u64* bwv = pw + (size_t)nb * MCOLS;

    void* args[] = {(void*)&P, (void*)&out, (void*)&pw, (void*)&bwv,
                    (void*)&n, (void*)&nb, (void*)&rpb};
    hipLaunchCooperativeKernel((void*)sinkhorn_v7, dim3(nb), dim3(256),
                               args, 0, stream);
}

// Round 2
// 733.974 us; speedup vs baseline: 1.0337x; 1.0104x over previous
//
#include <hip/hip_runtime.h>

#define KCOLS 7
#define MCOLS 8
#define LDSCH 768     // 4-row chunks cached in LDS  (3072 rows, 48 KB)
#define CACHECH 1024  // total cached chunks incl. 256 register chunks (4096 rows)
#define NB_PREF 512
#define NREP_PREF 64  // broadcast replicas (distinct 64B lines)
#define TAGM 0x7fffffffu

typedef unsigned long long u64;

// self-validating word: high32 = tag (| stop bit31 for broadcast), low32 = f32 bits
__device__ __forceinline__ u64 mkword(unsigned tag, float v) {
    return ((u64)tag << 32) | (u64)__float_as_uint(v);
}
__device__ __forceinline__ void st_rel(u64* p, u64 w) {
    __hip_atomic_store(p, w, __ATOMIC_RELAXED, __HIP_MEMORY_SCOPE_AGENT);
}
__device__ __forceinline__ u64 ld_rel(const u64* p) {
    return __hip_atomic_load(p, __ATOMIC_RELAXED, __HIP_MEMORY_SCOPE_AGENT);
}

// round-to-nearest-even pack of two f32 into bf16x2 (lo=a, hi=b)
__device__ __forceinline__ uint32_t pk_bf16(float a, float b) {
    uint32_t ua = __float_as_uint(a), ub = __float_as_uint(b);
    ua += 0x7FFFu + ((ua >> 16) & 1u);
    ub += 0x7FFFu + ((ub >> 16) & 1u);
    return (ua >> 16) | (ub & 0xFFFF0000u);
}
__device__ __forceinline__ void unp(uint32_t u, float& lo, float& hi) {
    lo = __uint_as_float(u << 16);
    hi = __uint_as_float(u & 0xFFFF0000u);
}
__device__ __forceinline__ float rcp_nr(float d) {
    float r = __builtin_amdgcn_rcpf(d);
    return fmaf(fmaf(-d, r, 1.0f), r, r);  // one Newton step -> ~1e-7 rel
}
// q = softmax(p)^10 (f32), sq = sum q
__device__ __forceinline__ void softmax10(const float* p, float* q, float& sq) {
    float mx = p[0];
#pragma unroll
    for (int j = 1; j < KCOLS; ++j) mx = fmaxf(mx, p[j]);
    float s = 0.0f;
#pragma unroll
    for (int j = 0; j < KCOLS; ++j) s += __expf(p[j] - mx);
    const float ls10 = 10.0f * __logf(s);
    sq = 0.0f;
#pragma unroll
    for (int j = 0; j < KCOLS; ++j) {
        q[j] = __expf(fmaf(10.0f, p[j] - mx, -ls10));
        sq += q[j];
    }
}

__device__ __forceinline__ void setup_chunk(const float4* Pv, size_t f4base,
                                            float* acc, uint4* qq) {
    union { float4 v4[7]; float f[28]; } u;
#pragma unroll
    for (int i = 0; i < 7; ++i) u.v4[i] = Pv[f4base + i];
#pragma unroll
    for (int k = 0; k < 4; ++k) {
        float q[KCOLS], sq;
        softmax10(u.f + k * 7, q, sq);
        qq[k] = make_uint4(pk_bf16(q[0], q[1]), pk_bf16(q[2], q[3]),
                           pk_bf16(q[4], q[5]), pk_bf16(q[6], 1.0f));
        const float rr = rcp_nr(0.125f * (sq + 1.0f));   // fold iter 1, b0=1/8
#pragma unroll
        for (int j = 0; j < KCOLS; ++j) acc[j] = fmaf(q[j], rr, acc[j]);
        acc[KCOLS] += rr;
    }
}

__device__ __forceinline__ void cached_row(uint4 u, const float* bf, float* acc) {
    float f0, f1, f2, f3, f4, f5, f6, f7;
    unp(u.x, f0, f1); unp(u.y, f2, f3); unp(u.z, f4, f5); unp(u.w, f6, f7);
    float dot = f0 * bf[0];
    dot = fmaf(f1, bf[1], dot); dot = fmaf(f2, bf[2], dot);
    dot = fmaf(f3, bf[3], dot); dot = fmaf(f4, bf[4], dot);
    dot = fmaf(f5, bf[5], dot); dot = fmaf(f6, bf[6], dot);
    dot = fmaf(f7, bf[7], dot);
    const float rr = rcp_nr(dot);
    acc[0] = fmaf(f0, rr, acc[0]); acc[1] = fmaf(f1, rr, acc[1]);
    acc[2] = fmaf(f2, rr, acc[2]); acc[3] = fmaf(f3, rr, acc[3]);
    acc[4] = fmaf(f4, rr, acc[4]); acc[5] = fmaf(f5, rr, acc[5]);
    acc[6] = fmaf(f6, rr, acc[6]); acc[7] = fmaf(f7, rr, acc[7]);
}

__device__ __forceinline__ void stream_chunk(const float4* Pv, size_t f4base,
                                             const float* bf, float* acc) {
    union { float4 v4[7]; float f[28]; } u;
#pragma unroll
    for (int i = 0; i < 7; ++i) u.v4[i] = Pv[f4base + i];
#pragma unroll
    for (int k = 0; k < 4; ++k) {
        float q[KCOLS], sq;
        softmax10(u.f + k * 7, q, sq);
        float dot = bf[KCOLS];
#pragma unroll
        for (int j = 0; j < KCOLS; ++j) dot = fmaf(q[j], bf[j], dot);
        const float rr = rcp_nr(dot);
#pragma unroll
        for (int j = 0; j < KCOLS; ++j) acc[j] = fmaf(q[j], rr, acc[j]);
        acc[KCOLS] += rr;
    }
}

__device__ __forceinline__ void final_chunk(const float4* Pv, float4* Ov, size_t f4base,
                                            const float* bpf, const float* bfin) {
    union { float4 v4[7]; float f[28]; } u;
    union { float4 v4[7]; float f[28]; } o;
#pragma unroll
    for (int i = 0; i < 7; ++i) u.v4[i] = Pv[f4base + i];
#pragma unroll
    for (int k = 0; k < 4; ++k) {
        float q[KCOLS], sq;
        softmax10(u.f + k * 7, q, sq);
        float dot = bpf[KCOLS];
#pragma unroll
        for (int j = 0; j < KCOLS; ++j) dot = fmaf(q[j], bpf[j], dot);
        const float rr = rcp_nr(dot);
#pragma unroll
        for (int j = 0; j < KCOLS; ++j) o.f[k * 7 + j] = q[j] * bfin[j] * rr;
    }
#pragma unroll
    for (int i = 0; i < 7; ++i) Ov[f4base + i] = o.v4[i];
}

// Persistent cooperative Sinkhorn, FENCE-FREE leader-broadcast sync:
// all cross-block words are (tag<<32 | f32) relaxed agent atomics -> no
// buffer_inv / wbl2 storms. Single buffer (no parity): the dependency chain
// leader-consumes(it) -> broadcast(it) -> workers-publish(it+1) makes
// overwrite-before-read impossible; tags are strictly monotone.
// v8: REPLICATED broadcast. v7's single 64B bw line was polled by ~4088
// threads continuously -> the line's coherence-point queue saturates and the
// leader's store + every follower's load serialize behind the poll storm.
// Now bw has nrep (64) replica lines; block bx polls replica bx&(nrep-1)
// (~8 blocks x 8 threads per line). Leader scatter-stores all replica words
// (2 per thread, independent, each self-validating) -> broadcast latency is
// one low-contention round trip.
// pw[bx*8+j]: block partials.  bw[r*8+j]: replicated b broadcast (stop bit63).
__global__ __launch_bounds__(256, 2)
void sinkhorn_v8(const float* __restrict__ P, float* __restrict__ out,
                 u64* __restrict__ pw, u64* __restrict__ bw,
                 int n, int nb, int rpb, int nrep) {
    const int tid = threadIdx.x, bx = blockIdx.x;
    const int lane = tid & 63, wv = tid >> 6;
    const double inv_n = 1.0 / (double)n;
    const double fi = 1.0 / 1.1;  // GAMMA/(GAMMA+EPSILON)
    const double Pb[MCOLS] = {0.17, 0.14, 0.15, 0.12, 0.05, 0.13, 0.24, 0.0};

    __shared__ uint4 qsh[LDSCH * 4];     // 48 KB
    __shared__ double wred[4][MCOLS];
    __shared__ double bn_sh[MCOLS];
    __shared__ float bf_sh[MCOLS];
    __shared__ int stop_sh;

    const int row0 = bx * rpb;           // rpb multiple of 4
    int rows_here = n - row0;
    if (rows_here > rpb) rows_here = rpb;
    if (rows_here < 0) rows_here = 0;
    const int nch = rows_here >> 2;
    const int nlds = (nch < LDSCH) ? nch : LDSCH;
    const int ncached = (nch < CACHECH) ? nch : CACHECH;
    const size_t base4 = (size_t)(row0 >> 2) * 7;
    const float4* Pv = (const float4*)P;

    uint4 rq[4];
    const int crg = LDSCH + tid;
    const bool have_reg = (crg < ncached);

    // ---------------- setup pass: read P, cache q, fold iteration 1 --------
    float acc[MCOLS];
#pragma unroll
    for (int j = 0; j < MCOLS; ++j) acc[j] = 0.0f;

#pragma unroll
    for (int jj = 0; jj < 3; ++jj) {
        const int c = tid + 256 * jj;
        if (c < nlds) {
            uint4 qq[4];
            setup_chunk(Pv, base4 + (size_t)c * 7, acc, qq);
#pragma unroll
            for (int k = 0; k < 4; ++k) qsh[c * 4 + k] = qq[k];
        }
    }
    if (have_reg) setup_chunk(Pv, base4 + (size_t)crg * 7, acc, rq);
    for (int c = CACHECH + tid; c < nch; c += 256) {
        uint4 qq[4];
        setup_chunk(Pv, base4 + (size_t)c * 7, acc, qq);
    }
    for (int r = (nch << 2) + tid; r < rows_here; r += 256) {
        float p[KCOLS];
        const float* row = P + (size_t)(row0 + r) * KCOLS;
        for (int j = 0; j < KCOLS; ++j) p[j] = row[j];
        float q[KCOLS], sq;
        softmax10(p, q, sq);
        const float rr = rcp_nr(0.125f * (sq + 1.0f));
        for (int j = 0; j < KCOLS; ++j) acc[j] = fmaf(q[j], rr, acc[j]);
        acc[KCOLS] += rr;
    }

    // block reduce -> publish tagged partial words (tag 1)
#pragma unroll
    for (int j = 0; j < MCOLS; ++j) {
        float v = acc[j];
#pragma unroll
        for (int off = 32; off > 0; off >>= 1) v += __shfl_down(v, off, 64);
        if (lane == 0) wred[wv][j] = (double)v;
    }
    __syncthreads();
    if (tid < MCOLS)
        st_rel(pw + bx * MCOLS + tid,
               mkword(1u, (float)(wred[0][tid] + wred[1][tid] +
                                  wred[2][tid] + wred[3][tid])));

    // ---------------- Sinkhorn loop ---------------------------------------
    double b64[MCOLS];
#pragma unroll
    for (int j = 0; j < MCOLS; ++j) b64[j] = 0.125;
    float bff[MCOLS], bpf[MCOLS];
#pragma unroll
    for (int j = 0; j < MCOLS; ++j) { bff[j] = 0.125f; bpf[j] = 0.125f; }

    // leader gather stripes: nb <= 512 always (launch clamps), 256 threads
    const u64* wp0 = pw + (size_t)tid * MCOLS;
    const u64* wp1 = pw + (size_t)(tid + 256) * MCOLS;
    const bool h0 = (tid < nb);
    const bool h1 = (tid + 256 < nb);
    // this block's broadcast replica line
    u64* bwr = bw + (size_t)(bx & (nrep - 1)) * MCOLS;
    const int nrw = nrep * MCOLS;        // total replica words (<= 512)

    for (int it = 1; it <= 50; ++it) {
        const unsigned want = (unsigned)it;
        int stop;
        if (bx == 0) {
            // ---- leader: batched poll of all partials, reduce, broadcast --
            u64 w0[MCOLS], w1[MCOLS];
            for (;;) {
                unsigned bad = 0;
                if (h0) {
#pragma unroll
                    for (int j = 0; j < MCOLS; ++j) w0[j] = ld_rel(wp0 + j);
                }
                if (h1) {
#pragma unroll
                    for (int j = 0; j < MCOLS; ++j) w1[j] = ld_rel(wp1 + j);
                }
                if (h0) {
#pragma unroll
                    for (int j = 0; j < MCOLS; ++j)
                        bad |= ((unsigned)(w0[j] >> 32)) ^ want;
                }
                if (h1) {
#pragma unroll
                    for (int j = 0; j < MCOLS; ++j)
                        bad |= ((unsigned)(w1[j] >> 32)) ^ want;
                }
                if (!bad) break;
                __builtin_amdgcn_s_sleep(1);
            }
            double c8[MCOLS];
#pragma unroll
            for (int j = 0; j < MCOLS; ++j) {
                double v = 0.0;
                if (h0) v += (double)__uint_as_float((unsigned)w0[j]);
                if (h1) v += (double)__uint_as_float((unsigned)w1[j]);
                c8[j] = v;
            }
#pragma unroll
            for (int j = 0; j < MCOLS; ++j) {   // fixed f64 tree -> deterministic
                double v = c8[j];
#pragma unroll
                for (int off = 32; off > 0; off >>= 1) v += __shfl_down(v, off, 64);
                if (lane == 0) wred[wv][j] = v;
            }
            __syncthreads();
            if (tid < MCOLS) {
                double c = wred[0][tid] + wred[1][tid] + wred[2][tid] + wred[3][tid];
                c *= inv_n;
                bn_sh[tid] = (tid < KCOLS) ? pow(Pb[tid] / c, fi) : 0.0;
            }
            __syncthreads();
            double err2 = 0.0;
#pragma unroll
            for (int j = 0; j < MCOLS; ++j) {
                const double d = bn_sh[j] - b64[j];
                err2 += d * d;
            }
            stop = (err2 <= 1e-12 || it == 50) ? 1 : 0;
            // scatter-store ALL replica lines (2 words/thread, independent)
            const unsigned tag = want | (stop ? 0x80000000u : 0u);
            for (int w = tid; w < nrw; w += 256)
                st_rel(bw + w, mkword(tag, (float)bn_sh[w & 7]));
#pragma unroll
            for (int j = 0; j < MCOLS; ++j) {
                bpf[j] = (float)b64[j];
                b64[j] = bn_sh[j];
                bff[j] = (float)b64[j];
            }
        } else {
            // ---- follower: 8 threads poll this block's replica line ------
            if (tid < MCOLS) {
                u64 w;
                while ((unsigned)(((w = ld_rel(bwr + tid)) >> 32) & TAGM) != want)
                    __builtin_amdgcn_s_sleep(1);
                bf_sh[tid] = __uint_as_float((unsigned)w);
                if (tid == 0) stop_sh = (int)(w >> 63);
            }
            __syncthreads();
            stop = stop_sh;
#pragma unroll
            for (int j = 0; j < MCOLS; ++j) {
                bpf[j] = bff[j];
                bff[j] = bf_sh[j];
            }
        }
        if (stop) break;

        // ---- compute pass with new b ----------------------------------
        float a2[MCOLS];
#pragma unroll
        for (int j = 0; j < MCOLS; ++j) a2[j] = 0.0f;
#pragma unroll
        for (int jj = 0; jj < 12; ++jj) {
            const int r = tid + 256 * jj;
            if (r < nlds * 4) cached_row(qsh[r], bff, a2);
        }
        if (have_reg) {
#pragma unroll
            for (int k = 0; k < 4; ++k) cached_row(rq[k], bff, a2);
        }
        for (int c = CACHECH + tid; c < nch; c += 256)
            stream_chunk(Pv, base4 + (size_t)c * 7, bff, a2);
        for (int r = (nch << 2) + tid; r < rows_here; r += 256) {
            float p2[KCOLS];
            const float* row = P + (size_t)(row0 + r) * KCOLS;
            for (int j = 0; j < KCOLS; ++j) p2[j] = row[j];
            float q[KCOLS], sq;
            softmax10(p2, q, sq);
            float dot = bff[KCOLS];
            for (int j = 0; j < KCOLS; ++j) dot = fmaf(q[j], bff[j], dot);
            const float rr = rcp_nr(dot);
            for (int j = 0; j < KCOLS; ++j) a2[j] = fmaf(q[j], rr, a2[j]);
            a2[KCOLS] += rr;
        }

#pragma unroll
        for (int j = 0; j < MCOLS; ++j) {
            float v = a2[j];
#pragma unroll
            for (int off = 32; off > 0; off >>= 1) v += __shfl_down(v, off, 64);
            if (lane == 0) wred[wv][j] = (double)v;
        }
        __syncthreads();
        if (tid < MCOLS)
            st_rel(pw + bx * MCOLS + tid,
                   mkword((unsigned)(it + 1),
                          (float)(wred[0][tid] + wred[1][tid] +
                                  wred[2][tid] + wred[3][tid])));
    }

    // ---------------- final pass: exact f32 q from P, write plan -----------
    float4* Ov = (float4*)out;
    for (int c = tid; c < nch; c += 256)
        final_chunk(Pv, Ov, base4 + (size_t)c * 7, bpf, bff);
    for (int r = (nch << 2) + tid; r < rows_here; r += 256) {
        float p[KCOLS];
        const float* row = P + (size_t)(row0 + r) * KCOLS;
        for (int j = 0; j < KCOLS; ++j) p[j] = row[j];
        float q[KCOLS], sq;
        softmax10(p, q, sq);
        float dot = bpf[KCOLS];
        for (int j = 0; j < KCOLS; ++j) dot = fmaf(q[j], bpf[j], dot);
        const float rr = rcp_nr(dot);
        float* orow = out + (size_t)(row0 + r) * KCOLS;
        for (int j = 0; j < KCOLS; ++j) orow[j] = q[j] * bff[j] * rr;
    }
}

extern "C" void kernel_launch(void* const* d_in, const int* in_sizes, int n_in,
                              void* d_out, int out_size, void* d_ws, size_t ws_size,
                              hipStream_t stream) {
    (void)n_in; (void)out_size;
    const float* P = (const float*)d_in[0];
    float* out = (float*)d_out;
    const int n = in_sizes[0] / KCOLS;

    int dev = 0;
    hipGetDevice(&dev);
    int cus = 0;
    hipDeviceGetAttribute(&cus, hipDeviceAttributeMultiprocessorCount, dev);
    if (cus <= 0) cus = 256;
    int maxb = 0;
    if (hipOccupancyMaxActiveBlocksPerMultiprocessor(&maxb, sinkhorn_v8, 256, 0) != hipSuccess || maxb < 1)
        maxb = 1;

    long long cap = (long long)maxb * cus;
    int nb = NB_PREF;
    if (nb > cap) nb = (int)cap;
    int nrep = NREP_PREF;
    // ws layout: pw[nb*8] then bw[nrep*8] (u64 each)
    while (nb > 64 &&
           (size_t)((nb + nrep) * MCOLS * sizeof(u64)) > ws_size) nb >>= 1;
    while (nrep > 1 &&
           (size_t)((nb + nrep) * MCOLS * sizeof(u64)) > ws_size) nrep >>= 1;
    if (nb < 2) nb = 2;
    int rpb = (((n + nb - 1) / nb) + 3) & ~3;   // nb=512, n=2^21 -> 4096 exact

    u64* pw = (u64*)d_ws;
    u64* bwv = pw + (size_t)nb * MCOLS;

    void* args[] = {(void*)&P, (void*)&out, (void*)&pw, (void*)&bwv,
                    (void*)&n, (void*)&nb, (void*)&rpb, (void*)&nrep};
    hipLaunchCooperativeKernel((void*)sinkhorn_v8, dim3(nb), dim3(256),
                               args, 0, stream);
}

// Round 3
// 491.029 us; speedup vs baseline: 1.5452x; 1.4948x over previous
//
#include <hip/hip_runtime.h>

#define KCOLS 7
#define MCOLS 8
#define LDSCH 768     // 4-row chunks cached in LDS  (3072 rows, 48 KB)
#define CACHECH 1024  // total cached chunks incl. 256 register chunks (4096 rows)
#define NB_PREF 512
#define TAGM 0x7fffffffu

typedef unsigned long long u64;

// self-validating word: high32 = tag (| stop bit31 for broadcast), low32 = f32 bits
__device__ __forceinline__ u64 mkword(unsigned tag, float v) {
    return ((u64)tag << 32) | (u64)__float_as_uint(v);
}
__device__ __forceinline__ void st_rel(u64* p, u64 w) {
    __hip_atomic_store(p, w, __ATOMIC_RELAXED, __HIP_MEMORY_SCOPE_AGENT);
}
__device__ __forceinline__ u64 ld_rel(const u64* p) {
    return __hip_atomic_load(p, __ATOMIC_RELAXED, __HIP_MEMORY_SCOPE_AGENT);
}

// round-to-nearest-even pack of two f32 into bf16x2 (lo=a, hi=b)
__device__ __forceinline__ uint32_t pk_bf16(float a, float b) {
    uint32_t ua = __float_as_uint(a), ub = __float_as_uint(b);
    ua += 0x7FFFu + ((ua >> 16) & 1u);
    ub += 0x7FFFu + ((ub >> 16) & 1u);
    return (ua >> 16) | (ub & 0xFFFF0000u);
}
__device__ __forceinline__ void unp(uint32_t u, float& lo, float& hi) {
    lo = __uint_as_float(u << 16);
    hi = __uint_as_float(u & 0xFFFF0000u);
}
__device__ __forceinline__ float rcp_nr(float d) {
    float r = __builtin_amdgcn_rcpf(d);
    return fmaf(fmaf(-d, r, 1.0f), r, r);  // one Newton step -> ~1e-7 rel
}
// q = softmax(p)^10 (f32), sq = sum q
__device__ __forceinline__ void softmax10(const float* p, float* q, float& sq) {
    float mx = p[0];
#pragma unroll
    for (int j = 1; j < KCOLS; ++j) mx = fmaxf(mx, p[j]);
    float s = 0.0f;
#pragma unroll
    for (int j = 0; j < KCOLS; ++j) s += __expf(p[j] - mx);
    const float ls10 = 10.0f * __logf(s);
    sq = 0.0f;
#pragma unroll
    for (int j = 0; j < KCOLS; ++j) {
        q[j] = __expf(fmaf(10.0f, p[j] - mx, -ls10));
        sq += q[j];
    }
}

// sum over lanes 0..7 (caller guarantees only lanes 0..7 active)
__device__ __forceinline__ double red8(double v) {
    v += __shfl_xor(v, 1);
    v += __shfl_xor(v, 2);
    v += __shfl_xor(v, 4);
    return v;
}
__device__ __forceinline__ int and8(int v) {
    v &= __shfl_xor(v, 1);
    v &= __shfl_xor(v, 2);
    v &= __shfl_xor(v, 4);
    return v;
}

__device__ __forceinline__ void setup_chunk(const float4* Pv, size_t f4base,
                                            float* acc, uint4* qq) {
    union { float4 v4[7]; float f[28]; } u;
#pragma unroll
    for (int i = 0; i < 7; ++i) u.v4[i] = Pv[f4base + i];
#pragma unroll
    for (int k = 0; k < 4; ++k) {
        float q[KCOLS], sq;
        softmax10(u.f + k * 7, q, sq);
        qq[k] = make_uint4(pk_bf16(q[0], q[1]), pk_bf16(q[2], q[3]),
                           pk_bf16(q[4], q[5]), pk_bf16(q[6], 1.0f));
        const float rr = rcp_nr(0.125f * (sq + 1.0f));   // fold iter 1, b0=1/8
#pragma unroll
        for (int j = 0; j < KCOLS; ++j) acc[j] = fmaf(q[j], rr, acc[j]);
        acc[KCOLS] += rr;
    }
}

__device__ __forceinline__ void cached_row(uint4 u, const float* bf, float* acc) {
    float f0, f1, f2, f3, f4, f5, f6, f7;
    unp(u.x, f0, f1); unp(u.y, f2, f3); unp(u.z, f4, f5); unp(u.w, f6, f7);
    float dot = f0 * bf[0];
    dot = fmaf(f1, bf[1], dot); dot = fmaf(f2, bf[2], dot);
    dot = fmaf(f3, bf[3], dot); dot = fmaf(f4, bf[4], dot);
    dot = fmaf(f5, bf[5], dot); dot = fmaf(f6, bf[6], dot);
    dot = fmaf(f7, bf[7], dot);
    const float rr = rcp_nr(dot);
    acc[0] = fmaf(f0, rr, acc[0]); acc[1] = fmaf(f1, rr, acc[1]);
    acc[2] = fmaf(f2, rr, acc[2]); acc[3] = fmaf(f3, rr, acc[3]);
    acc[4] = fmaf(f4, rr, acc[4]); acc[5] = fmaf(f5, rr, acc[5]);
    acc[6] = fmaf(f6, rr, acc[6]); acc[7] = fmaf(f7, rr, acc[7]);
}

__device__ __forceinline__ void final_chunk(const float4* Pv, float4* Ov, size_t f4base,
                                            const float* bpf, const float* bfin) {
    union { float4 v4[7]; float f[28]; } u;
    union { float4 v4[7]; float f[28]; } o;
#pragma unroll
    for (int i = 0; i < 7; ++i) u.v4[i] = Pv[f4base + i];
#pragma unroll
    for (int k = 0; k < 4; ++k) {
        float q[KCOLS], sq;
        softmax10(u.f + k * 7, q, sq);
        float dot = bpf[KCOLS];
#pragma unroll
        for (int j = 0; j < KCOLS; ++j) dot = fmaf(q[j], bpf[j], dot);
        const float rr = rcp_nr(dot);
#pragma unroll
        for (int j = 0; j < KCOLS; ++j) o.f[k * 7 + j] = q[j] * bfin[j] * rr;
    }
#pragma unroll
    for (int i = 0; i < 7; ++i) Ov[f4base + i] = o.v4[i];
}

// Persistent cooperative Sinkhorn, FENCE-FREE leader-broadcast sync
// (v7 config: single bw line, batched leader gather).
// v9: ANDERSON ACCELERATION (depth 3, f64, leader-only). R0-R2 showed the
// per-round cost (~9 us) is a cross-XCD visibility-latency floor, not
// contention (batching ~= null, replication regressed). So cut the ROUND
// COUNT: the global sums only evaluate the 8-dim fixed-point map b->G(c(b));
// the leader runs AA-II on the iterate sequence and broadcasts the
// accelerated point. Workers unchanged. Stop on plain-map residual
// ||G(c(b))-b||^2 <= 1e-12 (same convergence target as the reference's
// successive-difference criterion; plan sensitivity ~1e-6 << bf16-q floor).
// Guards (finite/range) fall back to the plain step + history reset, so the
// worst case degenerates to the previous 50-round behavior.
__global__ __launch_bounds__(256, 2)
void sinkhorn_v9(const float* __restrict__ P, float* __restrict__ out,
                 u64* __restrict__ pw, u64* __restrict__ bw,
                 int n, int nb, int rpb) {
    const int tid = threadIdx.x, bx = blockIdx.x;
    const int lane = tid & 63, wv = tid >> 6;
    const double inv_n = 1.0 / (double)n;
    const double fi = 1.0 / 1.1;  // GAMMA/(GAMMA+EPSILON)
    const double Pb[MCOLS] = {0.17, 0.14, 0.15, 0.12, 0.05, 0.13, 0.24, 0.0};

    __shared__ uint4 qsh[LDSCH * 4];     // 48 KB
    __shared__ double wred[4][MCOLS];
    __shared__ double bn_sh[MCOLS];      // f64 broadcast value
    __shared__ float bf_sh[MCOLS];       // follower poll result
    __shared__ float bprev_f_sh[MCOLS];  // leader: old point  -> bpf
    __shared__ float bnew_f_sh[MCOLS];   // leader: new point  -> bff
    __shared__ int stop_sh;

    const int row0 = bx * rpb;           // rpb multiple of 4
    int rows_here = n - row0;
    if (rows_here > rpb) rows_here = rpb;
    if (rows_here < 0) rows_here = 0;
    const int nch = rows_here >> 2;
    const int nlds = (nch < LDSCH) ? nch : LDSCH;
    const int ncached = (nch < CACHECH) ? nch : CACHECH;
    const size_t base4 = (size_t)(row0 >> 2) * 7;
    const float4* Pv = (const float4*)P;

    uint4 rq[4];
    const int crg = LDSCH + tid;
    const bool have_reg = (crg < ncached);

    // ---------------- setup pass: read P, cache q, fold iteration 1 --------
    float acc[MCOLS];
#pragma unroll
    for (int j = 0; j < MCOLS; ++j) acc[j] = 0.0f;

#pragma unroll
    for (int jj = 0; jj < 3; ++jj) {
        const int c = tid + 256 * jj;
        if (c < nlds) {
            uint4 qq[4];
            setup_chunk(Pv, base4 + (size_t)c * 7, acc, qq);
#pragma unroll
            for (int k = 0; k < 4; ++k) qsh[c * 4 + k] = qq[k];
        }
    }
    if (have_reg) setup_chunk(Pv, base4 + (size_t)crg * 7, acc, rq);
    for (int c = CACHECH + tid; c < nch; c += 256) {
        uint4 qq[4];
        setup_chunk(Pv, base4 + (size_t)c * 7, acc, qq);
    }
    for (int r = (nch << 2) + tid; r < rows_here; r += 256) {
        float p[KCOLS];
        const float* row = P + (size_t)(row0 + r) * KCOLS;
        for (int j = 0; j < KCOLS; ++j) p[j] = row[j];
        float q[KCOLS], sq;
        softmax10(p, q, sq);
        const float rr = rcp_nr(0.125f * (sq + 1.0f));
        for (int j = 0; j < KCOLS; ++j) acc[j] = fmaf(q[j], rr, acc[j]);
        acc[KCOLS] += rr;
    }

    // block reduce -> publish tagged partial words (tag 1)
#pragma unroll
    for (int j = 0; j < MCOLS; ++j) {
        float v = acc[j];
#pragma unroll
        for (int off = 32; off > 0; off >>= 1) v += __shfl_down(v, off, 64);
        if (lane == 0) wred[wv][j] = (double)v;
    }
    __syncthreads();
    if (tid < MCOLS)
        st_rel(pw + bx * MCOLS + tid,
               mkword(1u, (float)(wred[0][tid] + wred[1][tid] +
                                  wred[2][tid] + wred[3][tid])));

    // ---------------- Sinkhorn loop ---------------------------------------
    float bff[MCOLS], bpf[MCOLS];
#pragma unroll
    for (int j = 0; j < MCOLS; ++j) { bff[j] = 0.125f; bpf[j] = 0.125f; }

    // leader Anderson state (meaningful on wave0 lanes 0..7; per-lane = comp j)
    double bcur = 0.125;                 // current point b^(it-1), component j
    double Pf0 = 0.0, Pf1 = 0.0, Pf2 = 0.0;   // residual history (newest first)
    double Pg0 = 0.0, Pg1 = 0.0, Pg2 = 0.0;   // image history
    int histk = 0;

    // leader gather stripes: nb <= 512 always (launch clamps), 256 threads
    const u64* wp0 = pw + (size_t)tid * MCOLS;
    const u64* wp1 = pw + (size_t)(tid + 256) * MCOLS;
    const bool h0 = (tid < nb);
    const bool h1 = (tid + 256 < nb);

    for (int it = 1; it <= 50; ++it) {
        const unsigned want = (unsigned)it;
        int stop;
        if (bx == 0) {
            // ---- leader: batched poll of all partials, reduce -------------
            u64 w0[MCOLS], w1[MCOLS];
            for (;;) {
                unsigned bad = 0;
                if (h0) {
#pragma unroll
                    for (int j = 0; j < MCOLS; ++j) w0[j] = ld_rel(wp0 + j);
                }
                if (h1) {
#pragma unroll
                    for (int j = 0; j < MCOLS; ++j) w1[j] = ld_rel(wp1 + j);
                }
                if (h0) {
#pragma unroll
                    for (int j = 0; j < MCOLS; ++j)
                        bad |= ((unsigned)(w0[j] >> 32)) ^ want;
                }
                if (h1) {
#pragma unroll
                    for (int j = 0; j < MCOLS; ++j)
                        bad |= ((unsigned)(w1[j] >> 32)) ^ want;
                }
                if (!bad) break;
                __builtin_amdgcn_s_sleep(1);
            }
            double c8[MCOLS];
#pragma unroll
            for (int j = 0; j < MCOLS; ++j) {
                double v = 0.0;
                if (h0) v += (double)__uint_as_float((unsigned)w0[j]);
                if (h1) v += (double)__uint_as_float((unsigned)w1[j]);
                c8[j] = v;
            }
#pragma unroll
            for (int j = 0; j < MCOLS; ++j) {   // fixed f64 tree -> deterministic
                double v = c8[j];
#pragma unroll
                for (int off = 32; off > 0; off >>= 1) v += __shfl_down(v, off, 64);
                if (lane == 0) wred[wv][j] = v;
            }
            __syncthreads();
            if (tid < MCOLS)
                bn_sh[tid] = (wred[0][tid] + wred[1][tid] +
                              wred[2][tid] + wred[3][tid]) * inv_n;
            __syncthreads();
            // ---- Anderson-II (depth<=3) on wave0 lanes 0..7 ---------------
            if (wv == 0 && lane < MCOLS) {
                const int j = lane;
                const double cg = bn_sh[j];
                const double g = (j < KCOLS) ? pow(Pb[j] / cg, fi) : 0.0;
                const double f = g - bcur;
                const double rn2 = red8(f * f);
                const int st = (rn2 <= 1e-12 || it == 50) ? 1 : 0;
                double bnext = g;                     // plain step default
                if (!st && histk >= 1) {
                    const double dF0 = f - Pf0, dG0 = g - Pg0;
                    const double dF1 = Pf0 - Pf1, dG1 = Pg0 - Pg1;
                    const double dF2 = Pf1 - Pf2, dG2 = Pg1 - Pg2;
                    double g0 = 0.0, g1 = 0.0, g2 = 0.0;
                    int solved = 0;
                    if (histk == 1) {
                        const double A00 = red8(dF0 * dF0);
                        const double r0 = red8(dF0 * f);
                        const double d = A00 + 1e-12 * A00 + 1e-300;
                        g0 = r0 / d;
                        solved = 1;
                    } else if (histk == 2) {
                        double A00 = red8(dF0 * dF0);
                        const double A01 = red8(dF0 * dF1);
                        double A11 = red8(dF1 * dF1);
                        const double r0 = red8(dF0 * f);
                        const double r1 = red8(dF1 * f);
                        const double lam = 1e-12 * (A00 + A11) + 1e-300;
                        A00 += lam; A11 += lam;
                        const double det = A00 * A11 - A01 * A01;
                        if (fabs(det) > 1e-280) {
                            g0 = (r0 * A11 - A01 * r1) / det;
                            g1 = (A00 * r1 - A01 * r0) / det;
                            solved = 1;
                        }
                    } else {  // histk == 3
                        double A00 = red8(dF0 * dF0);
                        const double A01 = red8(dF0 * dF1);
                        const double A02 = red8(dF0 * dF2);
                        double A11 = red8(dF1 * dF1);
                        const double A12 = red8(dF1 * dF2);
                        double A22 = red8(dF2 * dF2);
                        const double r0 = red8(dF0 * f);
                        const double r1 = red8(dF1 * f);
                        const double r2 = red8(dF2 * f);
                        const double lam = 1e-12 * (A00 + A11 + A22) + 1e-300;
                        A00 += lam; A11 += lam; A22 += lam;
                        const double M00 = A11 * A22 - A12 * A12;
                        const double M01 = A01 * A22 - A12 * A02;
                        const double M02 = A01 * A12 - A11 * A02;
                        const double det = A00 * M00 - A01 * M01 + A02 * M02;
                        if (fabs(det) > 1e-280) {
                            const double M11 = A00 * A22 - A02 * A02;
                            const double M12 = A00 * A12 - A01 * A02;
                            const double M22 = A00 * A11 - A01 * A01;
                            g0 = ( r0 * M00 - r1 * M01 + r2 * M02) / det;
                            g1 = (-r0 * M01 + r1 * M11 - r2 * M12) / det;
                            g2 = ( r0 * M02 - r1 * M12 + r2 * M22) / det;
                            solved = 1;
                        }
                    }
                    if (solved) {
                        double cand = g - (g0 * dG0 + g1 * dG1 + g2 * dG2);
                        int ok = (j == KCOLS) ? 1
                                 : ((cand == cand) && cand > 1e-3 && cand < 100.0);
                        ok = and8(ok);
                        if (ok) {
                            bnext = (j < KCOLS) ? cand : 0.0;
                        } else {
                            histk = 0;            // reset history, plain step
                        }
                    } else {
                        histk = 0;
                    }
                }
                if (!st) {
                    // push (f, g) into history ring
                    Pf2 = Pf1; Pg2 = Pg1;
                    Pf1 = Pf0; Pg1 = Pg0;
                    Pf0 = f;   Pg0 = g;
                    histk = (histk < 3) ? histk + 1 : 3;
                }
                const double bb = st ? g : bnext;
                bprev_f_sh[j] = (float)bcur;
                bnew_f_sh[j] = (float)bb;
                bn_sh[j] = bb;
                if (j == 0) stop_sh = st;
                bcur = bb;
            }
            __syncthreads();
            stop = stop_sh;
            if (tid < MCOLS)
                st_rel(bw + tid, mkword(want | (stop ? 0x80000000u : 0u),
                                        (float)bn_sh[tid]));
#pragma unroll
            for (int j = 0; j < MCOLS; ++j) {
                bpf[j] = bprev_f_sh[j];
                bff[j] = bnew_f_sh[j];
            }
        } else {
            // ---- follower: 8 threads poll the 8 broadcast words ----------
            if (tid < MCOLS) {
                u64 w;
                while ((unsigned)(((w = ld_rel(bw + tid)) >> 32) & TAGM) != want)
                    __builtin_amdgcn_s_sleep(1);
                bf_sh[tid] = __uint_as_float((unsigned)w);
                if (tid == 0) stop_sh = (int)(w >> 63);
            }
            __syncthreads();
            stop = stop_sh;
#pragma unroll
            for (int j = 0; j < MCOLS; ++j) {
                bpf[j] = bff[j];
                bff[j] = bf_sh[j];
            }
        }
        if (stop) break;

        // ---- compute pass with new b ----------------------------------
        float a2[MCOLS];
#pragma unroll
        for (int j = 0; j < MCOLS; ++j) a2[j] = 0.0f;
#pragma unroll
        for (int jj = 0; jj < 12; ++jj) {
            const int r = tid + 256 * jj;
            if (r < nlds * 4) cached_row(qsh[r], bff, a2);
        }
        if (have_reg) {
#pragma unroll
            for (int k = 0; k < 4; ++k) cached_row(rq[k], bff, a2);
        }
        for (int c = CACHECH + tid; c < nch; c += 256) {
            union { float4 v4[7]; float f[28]; } u;
#pragma unroll
            for (int i = 0; i < 7; ++i) u.v4[i] = Pv[base4 + (size_t)c * 7 + i];
#pragma unroll
            for (int k = 0; k < 4; ++k) {
                float q[KCOLS], sq;
                softmax10(u.f + k * 7, q, sq);
                float dot = bff[KCOLS];
#pragma unroll
                for (int j = 0; j < KCOLS; ++j) dot = fmaf(q[j], bff[j], dot);
                const float rr = rcp_nr(dot);
#pragma unroll
                for (int j = 0; j < KCOLS; ++j) a2[j] = fmaf(q[j], rr, a2[j]);
                a2[KCOLS] += rr;
            }
        }
        for (int r = (nch << 2) + tid; r < rows_here; r += 256) {
            float p2[KCOLS];
            const float* row = P + (size_t)(row0 + r) * KCOLS;
            for (int j = 0; j < KCOLS; ++j) p2[j] = row[j];
            float q[KCOLS], sq;
            softmax10(p2, q, sq);
            float dot = bff[KCOLS];
            for (int j = 0; j < KCOLS; ++j) dot = fmaf(q[j], bff[j], dot);
            const float rr = rcp_nr(dot);
            for (int j = 0; j < KCOLS; ++j) a2[j] = fmaf(q[j], rr, a2[j]);
            a2[KCOLS] += rr;
        }

#pragma unroll
        for (int j = 0; j < MCOLS; ++j) {
            float v = a2[j];
#pragma unroll
            for (int off = 32; off > 0; off >>= 1) v += __shfl_down(v, off, 64);
            if (lane == 0) wred[wv][j] = (double)v;
        }
        __syncthreads();
        if (tid < MCOLS)
            st_rel(pw + bx * MCOLS + tid,
                   mkword((unsigned)(it + 1),
                          (float)(wred[0][tid] + wred[1][tid] +
                                  wred[2][tid] + wred[3][tid])));
    }

    // ---------------- final pass: exact f32 q from P, write plan -----------
    float4* Ov = (float4*)out;
    for (int c = tid; c < nch; c += 256)
        final_chunk(Pv, Ov, base4 + (size_t)c * 7, bpf, bff);
    for (int r = (nch << 2) + tid; r < rows_here; r += 256) {
        float p[KCOLS];
        const float* row = P + (size_t)(row0 + r) * KCOLS;
        for (int j = 0; j < KCOLS; ++j) p[j] = row[j];
        float q[KCOLS], sq;
        softmax10(p, q, sq);
        float dot = bpf[KCOLS];
        for (int j = 0; j < KCOLS; ++j) dot = fmaf(q[j], bpf[j], dot);
        const float rr = rcp_nr(dot);
        float* orow = out + (size_t)(row0 + r) * KCOLS;
        for (int j = 0; j < KCOLS; ++j) orow[j] = q[j] * bff[j] * rr;
    }
}

extern "C" void kernel_launch(void* const* d_in, const int* in_sizes, int n_in,
                              void* d_out, int out_size, void* d_ws, size_t ws_size,
                              hipStream_t stream) {
    (void)n_in; (void)out_size;
    const float* P = (const float*)d_in[0];
    float* out = (float*)d_out;
    const int n = in_sizes[0] / KCOLS;

    int dev = 0;
    hipGetDevice(&dev);
    int cus = 0;
    hipDeviceGetAttribute(&cus, hipDeviceAttributeMultiprocessorCount, dev);
    if (cus <= 0) cus = 256;
    int maxb = 0;
    if (hipOccupancyMaxActiveBlocksPerMultiprocessor(&maxb, sinkhorn_v9, 256, 0) != hipSuccess || maxb < 1)
        maxb = 1;

    long long cap = (long long)maxb * cus;
    int nb = NB_PREF;
    if (nb > cap) nb = (int)cap;
    while (nb > 64 && (size_t)((nb * MCOLS + MCOLS) * sizeof(u64)) > ws_size) nb >>= 1;
    if (nb < 2) nb = 2;
    int rpb = (((n + nb - 1) / nb) + 3) & ~3;   // nb=512, n=2^21 -> 4096 exact

    u64* pw = (u64*)d_ws;
    u64* bwv = pw + (size_t)nb * MCOLS;

    void* args[] = {(void*)&P, (void*)&out, (void*)&pw, (void*)&bwv,
                    (void*)&n, (void*)&nb, (void*)&rpb};
    hipLaunchCooperativeKernel((void*)sinkhorn_v9, dim3(nb), dim3(256),
                               args, 0, stream);
}